// Round 8
// baseline (7420.415 us; speedup 1.0000x reference)
//
#include <hip/hip_runtime.h>
#include <hip/hip_bf16.h>

#define B_   128
#define S_   512
#define I_   256
#define H_   256
#define G4   1024   // 4*H

// Journal R8. Measured history:
//  R3 5504us scan (1 wave/SIMD, latency-starved)
//  R4 7972us REGRESS (U read 2x/WG)
//  R5 4305us (split-k 1024thr, VALU 13%)
//  R7 4250us: bf16 U halved bytes -> NO CHANGE. Same load COUNT -> same dur.
//    => NOT L2-BW-bound; load-issue/latency-bound re-fetching constant U.
// R8: U-half register-resident (32 k-rows = 64 VGPR, static-indexed ureg),
// other 32 k-rows streamed in 4 batches of 8 dwordx2 (issue/cover/consume),
// h via ds_read_b128 (2k per read, broadcast). Load instrs 64->32/thread/step.
// VALU floor ~2.8us/step. Predict scan 1.7-2.3ms, VALUBusy 30-45%, VGPR~118.

__device__ __forceinline__ float masked_noise(float u, float n, float r) {
    float z = (u / (n + 1e-8f) + 1.0f) * 0.5f;
    float m = floorf(z + r);
    m = fminf(fmaxf(m, 0.0f), 1.0f);
    return n * (2.0f * m - 1.0f);
}

__device__ __forceinline__ float sigmoid_f(float x) {
    return 1.0f / (1.0f + __expf(-x));
}
__device__ __forceinline__ float tanh_f(float x) {
    float ax = fabsf(x);
    float t = __expf(-2.0f * ax);
    float r = (1.0f - t) / (1.0f + t);
    return copysignf(r, x);
}
__device__ __forceinline__ float uif(unsigned v) { return __uint_as_float(v); }
__device__ __forceinline__ float bf2f(unsigned short v) {
    return __uint_as_float((unsigned)v << 16);
}

// ---------------- prep: aW4 fp32 + aUb bf16, gate-interleaved [k][u][4] ----
__global__ __launch_bounds__(256) void prep_kernel(
    const float* __restrict__ W,  const float* __restrict__ uW,
    const float* __restrict__ nW, const float* __restrict__ rW,
    const float* __restrict__ U,  const float* __restrict__ uU,
    const float* __restrict__ nU, const float* __restrict__ rU,
    float* __restrict__ aW4, unsigned short* __restrict__ aUb) {
    int idx = blockIdx.x * 256 + threadIdx.x;
    const int n = I_ * G4;  // 262144
    if (idx < n) {
        float v = W[idx] + masked_noise(uW[idx], nW[idx], rW[idx]);
        int k = idx >> 10, col = idx & 1023;
        int g = col >> 8, j = col & 255;
        aW4[((size_t)(k << 8) + j) * 4 + g] = v;
    } else {
        int i2 = idx - n;
        float v = U[i2] + masked_noise(uU[i2], nU[i2], rU[i2]);
        int k = i2 >> 10, col = i2 & 1023;
        int g = col >> 8, j = col & 255;
        __hip_bfloat16 bv = __float2bfloat16(v);
        aUb[((size_t)(k << 8) + j) * 4 + g] = *(unsigned short*)&bv;
    }
}

// ---------------- xW = einsum('bsi,ig->sbg'), permuted columns --------------
template<int XW_BF16>
__global__ __launch_bounds__(256) void xw_gemm(
    const float* __restrict__ x, const float* __restrict__ aW4,
    void* __restrict__ xw_out) {
    __shared__ float xs[64][132];
    __shared__ float wt[64][68];
    const int tid = threadIdx.x;
    const int tx = tid & 15;
    const int ty = tid >> 4;
    const int bx = blockIdx.x;
    const int s  = blockIdx.y;

    float acc[8][4];
#pragma unroll
    for (int i = 0; i < 8; ++i)
#pragma unroll
        for (int j = 0; j < 4; ++j) acc[i][j] = 0.0f;

    for (int kc = 0; kc < 4; ++kc) {
#pragma unroll
        for (int t = 0; t < 8; ++t) {
            int e = tid + t * 256;
            int row = e >> 4;
            int kq  = e & 15;
            float4 v = *reinterpret_cast<const float4*>(
                &x[((size_t)row * S_ + s) * I_ + kc * 64 + kq * 4]);
            xs[kq * 4 + 0][row] = v.x;
            xs[kq * 4 + 1][row] = v.y;
            xs[kq * 4 + 2][row] = v.z;
            xs[kq * 4 + 3][row] = v.w;
        }
#pragma unroll
        for (int t = 0; t < 4; ++t) {
            int e = tid + t * 256;
            int kk = e >> 4;
            int cq = e & 15;
            float4 v = *reinterpret_cast<const float4*>(
                &aW4[((size_t)(kc * 64 + kk)) * G4 + bx * 64 + cq * 4]);
            *reinterpret_cast<float4*>(&wt[kk][cq * 4]) = v;
        }
        __syncthreads();

#pragma unroll 8
        for (int kk = 0; kk < 64; ++kk) {
            float4 a0 = *reinterpret_cast<const float4*>(&xs[kk][ty * 8]);
            float4 a1 = *reinterpret_cast<const float4*>(&xs[kk][ty * 8 + 4]);
            float4 bv = *reinterpret_cast<const float4*>(&wt[kk][tx * 4]);
            float a[8] = {a0.x, a0.y, a0.z, a0.w, a1.x, a1.y, a1.z, a1.w};
            float b[4] = {bv.x, bv.y, bv.z, bv.w};
#pragma unroll
            for (int i = 0; i < 8; ++i)
#pragma unroll
                for (int j = 0; j < 4; ++j) acc[i][j] += a[i] * b[j];
        }
        __syncthreads();
    }

#pragma unroll
    for (int i = 0; i < 8; ++i) {
        int row = ty * 8 + i;
        size_t off = ((size_t)s * B_ + row) * G4 + bx * 64 + tx * 4;
        if (XW_BF16) {
            __hip_bfloat16* xwb = (__hip_bfloat16*)xw_out;
            alignas(8) __hip_bfloat16 tmp[4];
#pragma unroll
            for (int j = 0; j < 4; ++j) tmp[j] = __float2bfloat16(acc[i][j]);
            *reinterpret_cast<ushort4*>(&xwb[off]) =
                *reinterpret_cast<const ushort4*>(tmp);
        } else {
            float* xwf = (float*)xw_out;
            float4 v = {acc[i][0], acc[i][1], acc[i][2], acc[i][3]};
            *reinterpret_cast<float4*>(&xwf[off]) = v;
        }
    }
}

// ---------------- LSTM scan: split-k, U-half in VGPRs ----------------------
// 64 blocks x 1024 thr; block owns batches {2*bid, 2*bid+1}.
// Thread (u=tid&255, kq=tid>>8): k in [kq*64, kq*64+64).
//   k rows kbase..kbase+31 : register-resident (uint2 ureg[32], static idx)
//   k rows kbase+32..+63   : streamed, 4 batches of 8 dwordx2
// h from hbuf[k][2] via float4 (2 k's, both batches, broadcast).
// Partials -> LDS part[4][8][256]; kq<2 threads reduce + act + own c/h.
template<int TIER>
__global__ __launch_bounds__(1024) void lstm_scan(
    const void* __restrict__ xw_in, const unsigned short* __restrict__ aUb,
    const float* __restrict__ aW4, const float* __restrict__ x,
    float* __restrict__ out) {
    const int tid = threadIdx.x;
    const int u   = tid & 255;
    const int kq  = tid >> 8;               // 0..3
    const int b0  = blockIdx.x * 2;
    const int kbase = kq * 64;

    __shared__ float hbuf[2][H_][2];        // [buf][k][bb]   4 KB
    __shared__ float part[4][8][256];       // [kq][slot][u] 32 KB
    __shared__ float xsh[I_][2];            // TIER2 only     2 KB

    if (tid < 512) hbuf[0][tid & 255][tid >> 8] = 0.0f;
    float c = 0.f, h = 0.f;                 // live on kq<2 threads (bb=kq)
    __syncthreads();

    const float*          xwf = (const float*)xw_in;
    const __hip_bfloat16* xwb = (const __hip_bfloat16*)xw_in;

    // register-resident U half: k = kbase + 0..31
    uint2 ureg[32];
    if (TIER != 2) {
#pragma unroll
        for (int i = 0; i < 32; ++i)
            ureg[i] = *reinterpret_cast<const uint2*>(
                &aUb[((size_t)(kbase + i) * 256 + u) * 4]);
    }

    for (int s = 0; s < S_; ++s) {
        const int cur = s & 1;

        float a00 = 0.f, a01 = 0.f, a02 = 0.f, a03 = 0.f;   // batch b0
        float a10 = 0.f, a11 = 0.f, a12 = 0.f, a13 = 0.f;   // batch b0+1
        float4 xg = {0.f, 0.f, 0.f, 0.f};

        if (TIER == 2) {
            // fallback: stream everything (rarely used; small-ws tier)
            if (tid < 512)
                xsh[tid & 255][tid >> 8] =
                    x[((size_t)(b0 + (tid >> 8)) * S_ + s) * I_ + (tid & 255)];
            __syncthreads();
            const float* Wb = aW4 + (size_t)kbase * G4 + ((size_t)u << 2);
#pragma unroll 16
            for (int kk = 0; kk < 64; ++kk) {
                float2 h2 = *reinterpret_cast<const float2*>(
                    &hbuf[cur][kbase + kk][0]);
                ushort4 uq = *reinterpret_cast<const ushort4*>(
                    &aUb[((size_t)(kbase + kk) * 256 + u) * 4]);
                float ux = bf2f(uq.x), uy = bf2f(uq.y);
                float uz = bf2f(uq.z), uw = bf2f(uq.w);
                a00 += h2.x * ux; a01 += h2.x * uy;
                a02 += h2.x * uz; a03 += h2.x * uw;
                a10 += h2.y * ux; a11 += h2.y * uy;
                a12 += h2.y * uz; a13 += h2.y * uw;
                float2 x2 = *reinterpret_cast<const float2*>(
                    &xsh[kbase + kk][0]);
                float4 wv = *reinterpret_cast<const float4*>(
                    &Wb[(size_t)kk * G4]);
                a00 += x2.x * wv.x; a01 += x2.x * wv.y;
                a02 += x2.x * wv.z; a03 += x2.x * wv.w;
                a10 += x2.y * wv.x; a11 += x2.y * wv.y;
                a12 += x2.y * wv.z; a13 += x2.y * wv.w;
            }
        } else {
            // xw prefetch on reduce-owner threads
            if (TIER == 0 && kq < 2) {
                xg = *reinterpret_cast<const float4*>(
                    &xwf[((size_t)s * B_ + b0 + kq) * G4 + ((size_t)u << 2)]);
            } else if (TIER == 1 && kq < 2) {
                ushort4 r = *reinterpret_cast<const ushort4*>(
                    &xwb[((size_t)s * B_ + b0 + kq) * G4 + ((size_t)u << 2)]);
                xg.x = bf2f(r.x); xg.y = bf2f(r.y);
                xg.z = bf2f(r.z); xg.w = bf2f(r.w);
            }

            uint2 sbuf[8];

// one k-pair of FMAs from packed uint2 (lo:{i,f} hi:{g,o} bf16)
#define PAIR_FMA(H4, LO0, HI0, LO1, HI1)                                   \
    {                                                                      \
        a00 += (H4).x * uif((LO0) << 16);                                  \
        a01 += (H4).x * uif((LO0) & 0xffff0000u);                          \
        a02 += (H4).x * uif((HI0) << 16);                                  \
        a03 += (H4).x * uif((HI0) & 0xffff0000u);                          \
        a10 += (H4).y * uif((LO0) << 16);                                  \
        a11 += (H4).y * uif((LO0) & 0xffff0000u);                          \
        a12 += (H4).y * uif((HI0) << 16);                                  \
        a13 += (H4).y * uif((HI0) & 0xffff0000u);                          \
        a00 += (H4).z * uif((LO1) << 16);                                  \
        a01 += (H4).z * uif((LO1) & 0xffff0000u);                          \
        a02 += (H4).z * uif((HI1) << 16);                                  \
        a03 += (H4).z * uif((HI1) & 0xffff0000u);                          \
        a10 += (H4).w * uif((LO1) << 16);                                  \
        a11 += (H4).w * uif((LO1) & 0xffff0000u);                          \
        a12 += (H4).w * uif((HI1) << 16);                                  \
        a13 += (H4).w * uif((HI1) & 0xffff0000u);                          \
    }

#define STR_ISSUE(BATCH)                                                   \
    {                                                                      \
        _Pragma("unroll") for (int i = 0; i < 8; ++i)                      \
            sbuf[i] = *reinterpret_cast<const uint2*>(                     \
                &aUb[((size_t)(kbase + 32 + (BATCH) * 8 + i) * 256 + u) * 4]); \
    }

#define REG_FMA(J0)                                                        \
    {                                                                      \
        _Pragma("unroll") for (int j = (J0); j < (J0) + 4; ++j) {          \
            float4 h4 = *reinterpret_cast<const float4*>(                  \
                &hbuf[cur][kbase + 2 * j][0]);                             \
            PAIR_FMA(h4, ureg[2 * j].x, ureg[2 * j].y,                     \
                     ureg[2 * j + 1].x, ureg[2 * j + 1].y);                \
        }                                                                  \
    }

#define STR_FMA(BATCH)                                                     \
    {                                                                      \
        _Pragma("unroll") for (int i = 0; i < 4; ++i) {                    \
            float4 h4 = *reinterpret_cast<const float4*>(                  \
                &hbuf[cur][kbase + 32 + (BATCH) * 8 + 2 * i][0]);          \
            PAIR_FMA(h4, sbuf[2 * i].x, sbuf[2 * i].y,                     \
                     sbuf[2 * i + 1].x, sbuf[2 * i + 1].y);                \
        }                                                                  \
    }

            STR_ISSUE(0)
            REG_FMA(0)
            STR_FMA(0)
            STR_ISSUE(1)
            REG_FMA(4)
            STR_FMA(1)
            STR_ISSUE(2)
            REG_FMA(8)
            STR_FMA(2)
            STR_ISSUE(3)
            REG_FMA(12)
            STR_FMA(3)

#undef PAIR_FMA
#undef STR_ISSUE
#undef REG_FMA
#undef STR_FMA
        }

        part[kq][0][u] = a00; part[kq][1][u] = a01;
        part[kq][2][u] = a02; part[kq][3][u] = a03;
        part[kq][4][u] = a10; part[kq][5][u] = a11;
        part[kq][6][u] = a12; part[kq][7][u] = a13;
        __syncthreads();

        if (kq < 2) {
            const int bb = kq;
            float gi = part[0][bb * 4 + 0][u] + part[1][bb * 4 + 0][u]
                     + part[2][bb * 4 + 0][u] + part[3][bb * 4 + 0][u];
            float gf = part[0][bb * 4 + 1][u] + part[1][bb * 4 + 1][u]
                     + part[2][bb * 4 + 1][u] + part[3][bb * 4 + 1][u];
            float gg = part[0][bb * 4 + 2][u] + part[1][bb * 4 + 2][u]
                     + part[2][bb * 4 + 2][u] + part[3][bb * 4 + 2][u];
            float go = part[0][bb * 4 + 3][u] + part[1][bb * 4 + 3][u]
                     + part[2][bb * 4 + 3][u] + part[3][bb * 4 + 3][u];

            float it = sigmoid_f(gi + xg.x);
            float ft = sigmoid_f(gf + xg.y);
            float gt = tanh_f(gg + xg.z);
            float ot = sigmoid_f(go + xg.w);
            c = ft * c + it * gt;
            h = ot * tanh_f(c);

            out[((size_t)(b0 + bb) * S_ + s) * H_ + u] = h;
            hbuf[cur ^ 1][u][bb] = h;
        }
        __syncthreads();
    }

    if (kq < 2) {
        const size_t HS = (size_t)B_ * S_ * H_;      // 16777216
        const size_t CS = (size_t)B_ * H_;           // 32768
        out[HS + (size_t)(b0 + kq) * H_ + u]      = h;
        out[HS + CS + (size_t)(b0 + kq) * H_ + u] = c;
    }
}

// ---------------- launch ----------------
extern "C" void kernel_launch(void* const* d_in, const int* in_sizes, int n_in,
                              void* d_out, int out_size, void* d_ws, size_t ws_size,
                              hipStream_t stream) {
    const float* x  = (const float*)d_in[0];
    const float* W  = (const float*)d_in[1];
    const float* U  = (const float*)d_in[2];
    const float* uW = (const float*)d_in[3];
    const float* nW = (const float*)d_in[4];
    const float* rW = (const float*)d_in[5];
    const float* uU = (const float*)d_in[6];
    const float* nU = (const float*)d_in[7];
    const float* rU = (const float*)d_in[8];

    float* ws  = (float*)d_ws;
    float*          aW4 = ws;                               // 262144 f (1 MB)
    unsigned short* aUb = (unsigned short*)(ws + 262144);   // 262144 us (512K)
    void*  xw  = (void*)(ws + 262144 + 131072);

    const size_t xw_elems  = (size_t)S_ * B_ * G4;          // 67108864
    const size_t base_f    = 262144 + 131072;
    const size_t need_fp32 = (base_f + xw_elems) * 4;       // ~270 MB
    const size_t need_bf16 = base_f * 4 + xw_elems * 2;     // ~136 MB

    prep_kernel<<<2048, 256, 0, stream>>>(W, uW, nW, rW, U, uU, nU, rU,
                                          aW4, aUb);

    dim3 ggrid(16, 512);
    if (ws_size >= need_fp32) {
        xw_gemm<0><<<ggrid, 256, 0, stream>>>(x, aW4, xw);
        lstm_scan<0><<<64, 1024, 0, stream>>>(xw, aUb, aW4, x, (float*)d_out);
    } else if (ws_size >= need_bf16) {
        xw_gemm<1><<<ggrid, 256, 0, stream>>>(x, aW4, xw);
        lstm_scan<1><<<64, 1024, 0, stream>>>(xw, aUb, aW4, x, (float*)d_out);
    } else {
        lstm_scan<2><<<64, 1024, 0, stream>>>(nullptr, aUb, aW4, x,
                                              (float*)d_out);
    }
}

// Round 11
// 2892.387 us; speedup vs baseline: 2.5655x; 2.5655x over previous
//
#include <hip/hip_runtime.h>
#include <hip/hip_bf16.h>

#define B_   128
#define S_   512
#define I_   256
#define H_   256
#define G4   1024   // 4*H

// Journal R11 (R9 kernel; benches R9+R10 both lost to GPUAcquisitionTimeout;
// resubmitting unchanged for clean attribution of 128WG + k-pair-uint4).
// Measured history:
//  R3 5504us scan (64WG x256thr, latency-starved)
//  R4 7972us REGRESS (U read 2x/WG)
//  R5 4305us (64WG x1024 split-k, fp32 U)
//  R7 4250us (bf16 U: halved bytes, same load count -> NO CHANGE)
//  R8 6843us REGRESS: ureg[32] SPILLED (VGPR=64 cap) -> FETCH 10.2GB scratch
//  Insight: Occ/VALU counters are chip-averages; 64 active CUs ran ~55% VALU.
// R9-R11: 128 WGs x 1024 thr, ONE batch per WG (2x CUs, halved per-CU VALU);
// U k-pair layout [k/2][u][8] bf16 -> 32 uint4 loads/thread/step (was 64);
// NO register-resident U (spill lesson). Port wall 3.7us + VALU 2.0us/step.
// Predict: scan 2.3-2.9ms, Occ ~24%, FETCH ~68MB (spill tripwire >100MB).

__device__ __forceinline__ float masked_noise(float u, float n, float r) {
    float z = (u / (n + 1e-8f) + 1.0f) * 0.5f;
    float m = floorf(z + r);
    m = fminf(fmaxf(m, 0.0f), 1.0f);
    return n * (2.0f * m - 1.0f);
}

__device__ __forceinline__ float sigmoid_f(float x) {
    return 1.0f / (1.0f + __expf(-x));
}
__device__ __forceinline__ float tanh_f(float x) {
    float ax = fabsf(x);
    float t = __expf(-2.0f * ax);
    float r = (1.0f - t) / (1.0f + t);
    return copysignf(r, x);
}
__device__ __forceinline__ float uif(unsigned v) { return __uint_as_float(v); }
__device__ __forceinline__ float bf2f(unsigned short v) {
    return __uint_as_float((unsigned)v << 16);
}

// ---------------- prep ----------------
// aW4 : fp32 gate-interleaved [k][u*4+g]          (GEMM + TIER2)
// aUb : bf16 k-pair layout  [k>>1][u][ (k&1)*4+g ] (scan: uint4 = 2k x 4g)
__global__ __launch_bounds__(256) void prep_kernel(
    const float* __restrict__ W,  const float* __restrict__ uW,
    const float* __restrict__ nW, const float* __restrict__ rW,
    const float* __restrict__ U,  const float* __restrict__ uU,
    const float* __restrict__ nU, const float* __restrict__ rU,
    float* __restrict__ aW4, unsigned short* __restrict__ aUb) {
    int idx = blockIdx.x * 256 + threadIdx.x;
    const int n = I_ * G4;  // 262144
    if (idx < n) {
        float v = W[idx] + masked_noise(uW[idx], nW[idx], rW[idx]);
        int k = idx >> 10, col = idx & 1023;
        int g = col >> 8, j = col & 255;
        aW4[((size_t)(k << 8) + j) * 4 + g] = v;
    } else {
        int i2 = idx - n;
        float v = U[i2] + masked_noise(uU[i2], nU[i2], rU[i2]);
        int k = i2 >> 10, col = i2 & 1023;
        int g = col >> 8, j = col & 255;
        __hip_bfloat16 bv = __float2bfloat16(v);
        aUb[(((size_t)(k >> 1) * 256 + j) << 3) + ((k & 1) << 2) + g] =
            *(unsigned short*)&bv;
    }
}

// ---------------- xW = einsum('bsi,ig->sbg'), permuted columns --------------
template<int XW_BF16>
__global__ __launch_bounds__(256) void xw_gemm(
    const float* __restrict__ x, const float* __restrict__ aW4,
    void* __restrict__ xw_out) {
    __shared__ float xs[64][132];
    __shared__ float wt[64][68];
    const int tid = threadIdx.x;
    const int tx = tid & 15;
    const int ty = tid >> 4;
    const int bx = blockIdx.x;
    const int s  = blockIdx.y;

    float acc[8][4];
#pragma unroll
    for (int i = 0; i < 8; ++i)
#pragma unroll
        for (int j = 0; j < 4; ++j) acc[i][j] = 0.0f;

    for (int kc = 0; kc < 4; ++kc) {
#pragma unroll
        for (int t = 0; t < 8; ++t) {
            int e = tid + t * 256;
            int row = e >> 4;
            int kq  = e & 15;
            float4 v = *reinterpret_cast<const float4*>(
                &x[((size_t)row * S_ + s) * I_ + kc * 64 + kq * 4]);
            xs[kq * 4 + 0][row] = v.x;
            xs[kq * 4 + 1][row] = v.y;
            xs[kq * 4 + 2][row] = v.z;
            xs[kq * 4 + 3][row] = v.w;
        }
#pragma unroll
        for (int t = 0; t < 4; ++t) {
            int e = tid + t * 256;
            int kk = e >> 4;
            int cq = e & 15;
            float4 v = *reinterpret_cast<const float4*>(
                &aW4[((size_t)(kc * 64 + kk)) * G4 + bx * 64 + cq * 4]);
            *reinterpret_cast<float4*>(&wt[kk][cq * 4]) = v;
        }
        __syncthreads();

#pragma unroll 8
        for (int kk = 0; kk < 64; ++kk) {
            float4 a0 = *reinterpret_cast<const float4*>(&xs[kk][ty * 8]);
            float4 a1 = *reinterpret_cast<const float4*>(&xs[kk][ty * 8 + 4]);
            float4 bv = *reinterpret_cast<const float4*>(&wt[kk][tx * 4]);
            float a[8] = {a0.x, a0.y, a0.z, a0.w, a1.x, a1.y, a1.z, a1.w};
            float b[4] = {bv.x, bv.y, bv.z, bv.w};
#pragma unroll
            for (int i = 0; i < 8; ++i)
#pragma unroll
                for (int j = 0; j < 4; ++j) acc[i][j] += a[i] * b[j];
        }
        __syncthreads();
    }

#pragma unroll
    for (int i = 0; i < 8; ++i) {
        int row = ty * 8 + i;
        size_t off = ((size_t)s * B_ + row) * G4 + bx * 64 + tx * 4;
        if (XW_BF16) {
            __hip_bfloat16* xwb = (__hip_bfloat16*)xw_out;
            alignas(8) __hip_bfloat16 tmp[4];
#pragma unroll
            for (int j = 0; j < 4; ++j) tmp[j] = __float2bfloat16(acc[i][j]);
            *reinterpret_cast<ushort4*>(&xwb[off]) =
                *reinterpret_cast<const ushort4*>(tmp);
        } else {
            float* xwf = (float*)xw_out;
            float4 v = {acc[i][0], acc[i][1], acc[i][2], acc[i][3]};
            *reinterpret_cast<float4*>(&xwf[off]) = v;
        }
    }
}

// ---------------- LSTM scan: 128 WGs, 1 batch/WG, split-k ------------------
// 128 blocks x 1024 thr; block owns batch b = blockIdx.x.
// Thread (u=tid&255, kq=tid>>8): gate partial sums over k in
// [kq*64, kq*64+64) = 32 k-pairs; one uint4 U load + one ds_read_b64 (h pair)
// + 8 unpack + 8 FMA per pair. kq>0 write partials to LDS; kq==0 reduces,
// activates, owns c/h. TIER: 0 fp32 xw, 1 bf16 xw, 2 fused.
template<int TIER>
__global__ __launch_bounds__(1024) void lstm_scan(
    const void* __restrict__ xw_in, const unsigned short* __restrict__ aUb,
    const float* __restrict__ aW4, const float* __restrict__ x,
    float* __restrict__ out) {
    const int tid = threadIdx.x;
    const int u   = tid & 255;
    const int kq  = tid >> 8;               // 0..3
    const int b   = blockIdx.x;

    __shared__ float hbuf[2][H_];           // [buf][k]       2 KB
    __shared__ float part[3][4][256];       // [kq-1][g][u]  12 KB
    __shared__ float xsh[I_];               // TIER2 x row    1 KB

    if (tid < 256) hbuf[0][tid] = 0.0f;
    float c = 0.f, h = 0.f;                 // live on kq==0 threads
    __syncthreads();

    const float*          xwf = (const float*)xw_in;
    const __hip_bfloat16* xwb = (const __hip_bfloat16*)xw_in;
    // U base for this thread's k-pair range: kp = kq*32 .. kq*32+31
    const uint4* Ub = reinterpret_cast<const uint4*>(aUb) +
                      ((size_t)kq * 32) * 256 + u;   // +kp*256 per pair

    for (int s = 0; s < S_; ++s) {
        const int cur = s & 1;

        if (TIER == 2) {
            if (tid < 256) xsh[tid] = x[((size_t)b * S_ + s) * I_ + tid];
            __syncthreads();
        }

        // xw prefetch on the reduce-owner quarter (waves 0-3, uniform)
        float4 xg = {0.f, 0.f, 0.f, 0.f};
        if (TIER == 0 && kq == 0) {
            xg = *reinterpret_cast<const float4*>(
                &xwf[((size_t)s * B_ + b) * G4 + ((size_t)u << 2)]);
        } else if (TIER == 1 && kq == 0) {
            ushort4 r = *reinterpret_cast<const ushort4*>(
                &xwb[((size_t)s * B_ + b) * G4 + ((size_t)u << 2)]);
            xg.x = bf2f(r.x); xg.y = bf2f(r.y);
            xg.z = bf2f(r.z); xg.w = bf2f(r.w);
        }

        float a0 = 0.f, a1 = 0.f, a2 = 0.f, a3 = 0.f;   // i,f,g,o

        if (TIER == 2) {
            const float* Wb = aW4 + ((size_t)kq * 64) * G4 + ((size_t)u << 2);
#pragma unroll 8
            for (int kk = 0; kk < 64; ++kk) {
                float hv = hbuf[cur][kq * 64 + kk];
                ushort4 uq = *reinterpret_cast<const ushort4*>(
                    &aUb[(((size_t)((kq * 64 + kk) >> 1) * 256 + u) << 3) +
                         (((kq * 64 + kk) & 1) << 2)]);
                a0 += hv * bf2f(uq.x); a1 += hv * bf2f(uq.y);
                a2 += hv * bf2f(uq.z); a3 += hv * bf2f(uq.w);
                float xv = xsh[kq * 64 + kk];
                float4 wv = *reinterpret_cast<const float4*>(
                    &Wb[(size_t)kk * G4]);
                a0 += xv * wv.x; a1 += xv * wv.y;
                a2 += xv * wv.z; a3 += xv * wv.w;
            }
        } else {
#pragma unroll 8
            for (int kp = 0; kp < 32; ++kp) {
                float2 h2 = *reinterpret_cast<const float2*>(
                    &hbuf[cur][(kq * 32 + kp) * 2]);
                uint4 uq = Ub[(size_t)kp * 256];
                // k even: uq.x = {i,f}, uq.y = {g,o}; k odd: uq.z, uq.w
                a0 += h2.x * uif(uq.x << 16);
                a1 += h2.x * uif(uq.x & 0xffff0000u);
                a2 += h2.x * uif(uq.y << 16);
                a3 += h2.x * uif(uq.y & 0xffff0000u);
                a0 += h2.y * uif(uq.z << 16);
                a1 += h2.y * uif(uq.z & 0xffff0000u);
                a2 += h2.y * uif(uq.w << 16);
                a3 += h2.y * uif(uq.w & 0xffff0000u);
            }
        }

        if (kq > 0) {
            part[kq - 1][0][u] = a0; part[kq - 1][1][u] = a1;
            part[kq - 1][2][u] = a2; part[kq - 1][3][u] = a3;
        }
        __syncthreads();

        if (kq == 0) {
            a0 += part[0][0][u] + part[1][0][u] + part[2][0][u];
            a1 += part[0][1][u] + part[1][1][u] + part[2][1][u];
            a2 += part[0][2][u] + part[1][2][u] + part[2][2][u];
            a3 += part[0][3][u] + part[1][3][u] + part[2][3][u];

            float it = sigmoid_f(a0 + xg.x);
            float ft = sigmoid_f(a1 + xg.y);
            float gt = tanh_f(a2 + xg.z);
            float ot = sigmoid_f(a3 + xg.w);
            c = ft * c + it * gt;
            h = ot * tanh_f(c);

            out[((size_t)b * S_ + s) * H_ + u] = h;
            hbuf[cur ^ 1][u] = h;
        }
        __syncthreads();
    }

    if (kq == 0) {
        const size_t HS = (size_t)B_ * S_ * H_;      // 16777216
        const size_t CS = (size_t)B_ * H_;           // 32768
        out[HS + (size_t)b * H_ + u]      = h;
        out[HS + CS + (size_t)b * H_ + u] = c;
    }
}

// ---------------- launch ----------------
extern "C" void kernel_launch(void* const* d_in, const int* in_sizes, int n_in,
                              void* d_out, int out_size, void* d_ws, size_t ws_size,
                              hipStream_t stream) {
    const float* x  = (const float*)d_in[0];
    const float* W  = (const float*)d_in[1];
    const float* U  = (const float*)d_in[2];
    const float* uW = (const float*)d_in[3];
    const float* nW = (const float*)d_in[4];
    const float* rW = (const float*)d_in[5];
    const float* uU = (const float*)d_in[6];
    const float* nU = (const float*)d_in[7];
    const float* rU = (const float*)d_in[8];

    float* ws  = (float*)d_ws;
    float*          aW4 = ws;                               // 262144 f (1 MB)
    unsigned short* aUb = (unsigned short*)(ws + 262144);   // 262144 us (512K)
    void*  xw  = (void*)(ws + 262144 + 131072);

    const size_t xw_elems  = (size_t)S_ * B_ * G4;          // 67108864
    const size_t base_f    = 262144 + 131072;
    const size_t need_fp32 = (base_f + xw_elems) * 4;       // ~270 MB
    const size_t need_bf16 = base_f * 4 + xw_elems * 2;     // ~136 MB

    prep_kernel<<<2048, 256, 0, stream>>>(W, uW, nW, rW, U, uU, nU, rU,
                                          aW4, aUb);

    dim3 ggrid(16, 512);
    if (ws_size >= need_fp32) {
        xw_gemm<0><<<ggrid, 256, 0, stream>>>(x, aW4, xw);
        lstm_scan<0><<<128, 1024, 0, stream>>>(xw, aUb, aW4, x, (float*)d_out);
    } else if (ws_size >= need_bf16) {
        xw_gemm<1><<<ggrid, 256, 0, stream>>>(x, aW4, xw);
        lstm_scan<1><<<128, 1024, 0, stream>>>(xw, aUb, aW4, x, (float*)d_out);
    } else {
        lstm_scan<2><<<128, 1024, 0, stream>>>(nullptr, aUb, aW4, x,
                                               (float*)d_out);
    }
}